// Round 13
// baseline (412.852 us; speedup 1.0000x reference)
//
#include <hip/hip_runtime.h>
#include <hip/hip_bf16.h>
#include <hip/hip_fp16.h>
#include <math.h>

#define N_NODES 100000
#define N_EDGES 3200000
#define N_GRAPHS 512
#define BN_EPS 1e-5f
#define NBIN ((N_NODES + 255) / 256)            // 391 bins of 256 nodes
#define CHUNK 8192                              // edges per chunk
#define NCHUNK ((N_EDGES + CHUNK - 1) / CHUNK)  // 391
#define STORE_CAP (N_EDGES + 16 * NBIN * NCHUNK)  // padded store capacity
#define STAGE_CAP 9216                          // per-bin stage (mean 8192 + 11 sigma)
#define LSEG 98
#define NSEGB ((N_NODES + LSEG - 1) / LSEG)     // 1021 pool segments
#define NSTATB ((N_NODES + 127) / 128)          // 782 stats slabs

typedef _Float16 half8_t __attribute__((ext_vector_type(8)));
typedef float float4_t __attribute__((ext_vector_type(4)));

struct alignas(8) h4 { __half2 a, b; };
struct alignas(16) h8s { __half2 h[4]; };

// ---------------- CSR build: padded single-scatter radix ----------------

__global__ void k_hist2(const int* __restrict__ dst, int* __restrict__ hists) {
    __shared__ int h[NBIN];
    for (int i = threadIdx.x; i < NBIN; i += blockDim.x) h[i] = 0;
    __syncthreads();
    int e0 = blockIdx.x * CHUNK;
    int e1 = min(e0 + CHUNK, N_EDGES);
    for (int e = e0 + threadIdx.x; e < e1; e += blockDim.x)
        atomicAdd(&h[dst[e] >> 8], 1);
    __syncthreads();
    for (int i = threadIdx.x; i < NBIN; i += blockDim.x)
        hists[i * NCHUNK + blockIdx.x] = h[i];
}

// per-bin exclusive scan over chunks of PADDED counts (pad to x16 -> 64B runs)
__global__ void k_scan2(int* __restrict__ hists, int* __restrict__ ghist) {
    int b = blockIdx.x;
    int lane = threadIdx.x;   // 64 threads
    int carry = 0;
    int base = b * NCHUNK;
    for (int c0 = 0; c0 < NCHUNK; c0 += 64) {
        int c = c0 + lane;
        int v = (c < NCHUNK) ? hists[base + c] : 0;
        int pv = (v + 15) & ~15;
        int inc = pv;
#pragma unroll
        for (int off = 1; off < 64; off <<= 1) {
            int u = __shfl_up(inc, off, 64);
            if (lane >= off) inc += u;
        }
        if (c < NCHUNK) hists[base + c] = inc - pv + carry;
        carry += __shfl(inc, 63, 64);
    }
    if (lane == 0) ghist[b] = carry;   // padded bin total
}

__global__ void k_binscan(const int* __restrict__ ghist, int* __restrict__ bbase) {
    __shared__ int sd[512];
    int t = threadIdx.x;
    int v = (t < NBIN) ? ghist[t] : 0;
    sd[t] = v;
    __syncthreads();
    for (int off = 1; off < 512; off <<= 1) {
        int u = (t >= off) ? sd[t - off] : 0;
        __syncthreads();
        sd[t] += u;
        __syncthreads();
    }
    if (t < NBIN) bbase[t] = sd[t] - v;
    if (t == 511) bbase[NBIN] = sd[511];   // padded grand total
}

// LDS-staged scatter: stage chunk in LDS, then copy runs out with full-line writes
__global__ void k_scatter(const int* __restrict__ src, const int* __restrict__ dst,
                          const int* __restrict__ bbase, const int* __restrict__ hists,
                          int* __restrict__ store) {
    __shared__ int lcnt[NBIN], sbase[NBIN], cur[NBIN];
    __shared__ int stage[CHUNK];
    int t = threadIdx.x;
    int wave = t >> 6, lane = t & 63;
    for (int i = t; i < NBIN; i += 256) lcnt[i] = 0;
    __syncthreads();
    int e0 = blockIdx.x * CHUNK;
    int e1 = min(e0 + CHUNK, N_EDGES);
    for (int e = e0 + t; e < e1; e += 256)
        atomicAdd(&lcnt[dst[e] >> 8], 1);
    __syncthreads();
    if (wave == 0) {   // compact exclusive scan lcnt -> sbase (and init cur)
        int carry = 0;
        for (int c0 = 0; c0 < NBIN; c0 += 64) {
            int i = c0 + lane;
            int v = (i < NBIN) ? lcnt[i] : 0;
            int inc = v;
#pragma unroll
            for (int off = 1; off < 64; off <<= 1) {
                int u = __shfl_up(inc, off, 64);
                if (lane >= off) inc += u;
            }
            if (i < NBIN) { sbase[i] = inc - v + carry; cur[i] = inc - v + carry; }
            carry += __shfl(inc, 63, 64);
        }
    }
    __syncthreads();
    for (int e = e0 + t; e < e1; e += 256) {
        int d = dst[e];
        int b = d >> 8;
        int pos = atomicAdd(&cur[b], 1);
        stage[pos] = (src[e] << 8) | (d & 255);
    }
    __syncthreads();
    // copy each bin's run to global (64B-aligned dest), sentinel-pad the tail
    for (int i = wave; i < NBIN; i += 4) {
        int s0 = sbase[i];
        int L = cur[i] - s0;
        int P = (L + 15) & ~15;
        int g = bbase[i] + hists[i * NCHUNK + blockIdx.x];
        for (int k = lane; k < P; k += 64)
            store[g + k] = (k < L) ? stage[s0 + k] : -1;
    }
}

__global__ void k_csr_build(const int* __restrict__ bbase, const int* __restrict__ store,
                            const float* __restrict__ x, int* __restrict__ offs,
                            int* __restrict__ ends, float* __restrict__ dis,
                            float* __restrict__ rdis, float4* __restrict__ xd,
                            int* __restrict__ csr) {
    __shared__ int cnt[256], cur[256], wsum[4];
    __shared__ int stage[STAGE_CAP];
    __shared__ int nstage;
    int b = blockIdx.x;
    int n0 = b << 8;
    int nn = min(256, N_NODES - n0);
    int e0 = bbase[b], e1 = bbase[b + 1];
    int t = threadIdx.x;
    int lane = t & 63, wid = t >> 6;
    cnt[t] = 0;
    if (t == 0) nstage = 0;
    __syncthreads();
    // ballot-compact real edges into LDS stage (skip sentinels)
    int eEnd = e0 + ((e1 - e0 + 255) & ~255);
    for (int e = e0 + t; e < eEnd; e += 256) {
        int p = (e < e1) ? store[e] : -1;
        unsigned long long mask = __ballot(p >= 0);
        int cw = __popcll(mask);
        int basew = 0;
        if (lane == 0 && cw) basew = atomicAdd(&nstage, cw);
        basew = __shfl(basew, 0, 64);
        if (p >= 0) {
            int idx = basew + __popcll(mask & ((1ULL << lane) - 1));
            if (idx < STAGE_CAP) stage[idx] = p;
        }
    }
    __syncthreads();
    int ne = min(nstage, STAGE_CAP);
    for (int i = t; i < ne; i += 256) atomicAdd(&cnt[stage[i] & 255], 1);
    __syncthreads();
    int c = cnt[t];
    int inc = c;
#pragma unroll
    for (int off = 1; off < 64; off <<= 1) {
        int u = __shfl_up(inc, off, 64);
        if (lane >= off) inc += u;
    }
    if (lane == 63) wsum[wid] = inc;
    __syncthreads();
    int wo = 0;
    for (int w = 0; w < wid; ++w) wo += wsum[w];
    int ex = inc - c + wo;
    cur[t] = ex;
    if (t < nn) {
        int n = n0 + t;
        offs[n] = e0 + ex;
        ends[n] = e0 + ex + c;
        float dn = rsqrtf(1.0f + (float)c);
        dis[n] = dn;
        rdis[n] = sqrtf(1.0f + (float)c);
        float2 xv = *(const float2*)(x + 2 * (size_t)n);
        xd[n] = make_float4(dn * xv.x, dn * xv.y, dn, 0.f);
    }
    if (n0 + t == N_NODES) xd[N_NODES] = make_float4(0.f, 0.f, 0.f, 0.f);
    __syncthreads();
    for (int i = t; i < ne; i += 256) {
        int p = stage[i];
        int pos = e0 + atomicAdd(&cur[p & 255], 1);
        csr[pos] = p >> 8;
    }
}

// ---------------- layer 1: 4 nodes/wave, aggregate xd + fused 2->8 mm + relu ----------------

__global__ void k_agg1(const float4* __restrict__ xd, const int* __restrict__ offs,
                       const int* __restrict__ ends, const int* __restrict__ csr,
                       const float* __restrict__ W1, const float* __restrict__ b1,
                       float* __restrict__ svec, __half* __restrict__ ys1) {
    __shared__ float sW[16], sb[8];
    int t = threadIdx.x;
    if (t < 16) sW[t] = W1[t];
    if (t < 8) sb[t] = b1[t];
    __syncthreads();
    int wave = t >> 6, lane = t & 63;
    int nsub = lane >> 4, eg = lane & 15;
    int node = ((blockIdx.x * 4 + wave) << 2) + nsub;   // exact: 100000 = 25000*4
    int e0 = offs[node], e1 = ends[node];
    float ax = 0.f, ay = 0.f, as = 0.f;
    for (int e = e0 + eg; e < e1; e += 32) {
        int s0 = csr[e];
        int s1 = (e + 16 < e1) ? csr[e + 16] : N_NODES;
        float4 v0 = xd[s0];
        float4 v1 = xd[s1];
        ax += v0.x + v1.x;
        ay += v0.y + v1.y;
        as += v0.z + v1.z;
    }
#pragma unroll
    for (int off = 1; off < 16; off <<= 1) {
        ax += __shfl_xor(ax, off, 64);
        ay += __shfl_xor(ay, off, 64);
        as += __shfl_xor(as, off, 64);
    }
    if (eg == 0) {
        float4 xn = xd[node];
        float dn = xn.z;
        float u0x = dn * (ax + xn.x);
        float u0y = dn * (ay + xn.y);
        svec[node] = dn * (as + xn.z);
        float y[8];
#pragma unroll
        for (int f = 0; f < 8; ++f)
            y[f] = dn * fmaxf(u0x * sW[f] + u0y * sW[8 + f] + sb[f], 0.f);
        h8s o;
#pragma unroll
        for (int q = 0; q < 4; ++q) o.h[q] = __floats2half2_rn(y[2 * q], y[2 * q + 1]);
        *(h8s*)(ys1 + (size_t)node * 8) = o;
    }
}

// ---------------- prep2: bn fold into W2; zero row ys1[N] ----------------

__global__ void k_prep2(const float* __restrict__ stats, const float* __restrict__ gamma,
                        const float* __restrict__ beta, const float* __restrict__ W2,
                        float* __restrict__ W2p, float* __restrict__ cw2,
                        __half* __restrict__ ys1) {
    __shared__ float a1[8], c1[8];
    int t = threadIdx.x;   // 256
    if (t < 8) {
        float inv_n = 1.0f / (float)N_NODES;
        float m = stats[t] * inv_n;
        float v = stats[8 + t] * inv_n - m * m;
        float a = gamma[t] * rsqrtf(v + BN_EPS);
        a1[t] = a;
        c1[t] = beta[t] - m * a;
    }
    __syncthreads();
    W2p[t] = a1[t >> 5] * W2[t];    // 8x32 = 256
    if (t < 32) {
        float cb = 0.f;
#pragma unroll
        for (int i = 0; i < 8; ++i) cb += c1[i] * W2[i * 32 + t];
        cw2[t] = cb;
    }
    if (t == 128) *(int4*)(ys1 + (size_t)N_NODES * 8) = make_int4(0, 0, 0, 0);
}

// ---------------- layer 2: 8 nodes/wave, aggregate ys1 (width 8) + fused 8->32 mm ----------------

__global__ void k_agg2(const __half* __restrict__ ys1, const int* __restrict__ offs,
                       const int* __restrict__ ends, const int* __restrict__ csr,
                       const float* __restrict__ dis, const float* __restrict__ svec,
                       const float* __restrict__ W2p, const float* __restrict__ cw2,
                       const float* __restrict__ b2, __half* __restrict__ ys2) {
    __shared__ float sW[256], sC[32], sB[32];
    int t = threadIdx.x;
    sW[t] = W2p[t];
    if (t < 32) { sC[t] = cw2[t]; sB[t] = b2[t]; }
    __syncthreads();
    int wave = t >> 6, lane = t & 63;
    int nsub = lane >> 3, eg = (lane >> 1) & 3, chunk = lane & 1;
    int node = ((blockIdx.x * 4 + wave) << 3) + nsub;   // exact: 100000 = 12500*8
    int e0 = offs[node], e1 = ends[node];
    float a0 = 0.f, a1 = 0.f, a2 = 0.f, a3 = 0.f;
    const __half* hp = ys1 + chunk * 4;
    for (int e = e0 + eg; e < e1; e += 8) {
        int s0 = csr[e];
        int s1 = (e + 4 < e1) ? csr[e + 4] : N_NODES;
        h4 v0 = *(const h4*)(hp + (size_t)s0 * 8);
        h4 v1 = *(const h4*)(hp + (size_t)s1 * 8);
        a0 += __low2float(v0.a) + __low2float(v1.a);
        a1 += __high2float(v0.a) + __high2float(v1.a);
        a2 += __low2float(v0.b) + __low2float(v1.b);
        a3 += __high2float(v0.b) + __high2float(v1.b);
    }
    if (eg == 0) {   // self-loop
        h4 v = *(const h4*)(hp + (size_t)node * 8);
        a0 += __low2float(v.a);
        a1 += __high2float(v.a);
        a2 += __low2float(v.b);
        a3 += __high2float(v.b);
    }
#pragma unroll
    for (int off = 2; off < 8; off <<= 1) {
        a0 += __shfl_xor(a0, off, 64);
        a1 += __shfl_xor(a1, off, 64);
        a2 += __shfl_xor(a2, off, 64);
        a3 += __shfl_xor(a3, off, 64);
    }
    int lb = nsub << 3;
    float u[8];
    u[0] = __shfl(a0, lb, 64);     u[1] = __shfl(a1, lb, 64);
    u[2] = __shfl(a2, lb, 64);     u[3] = __shfl(a3, lb, 64);
    u[4] = __shfl(a0, lb + 1, 64); u[5] = __shfl(a1, lb + 1, 64);
    u[6] = __shfl(a2, lb + 1, 64); u[7] = __shfl(a3, lb + 1, 64);
    float dn = dis[node];
    float sv = svec[node];
#pragma unroll
    for (int i = 0; i < 8; ++i) u[i] *= dn;
    int c0 = (lane & 7) * 4;
    float y[4];
#pragma unroll
    for (int k = 0; k < 4; ++k) {
        int col = c0 + k;
        float conv = sB[col] + sv * sC[col];
#pragma unroll
        for (int i = 0; i < 8; ++i) conv += u[i] * sW[i * 32 + col];
        y[k] = dn * fmaxf(conv, 0.f);
    }
    h4 o;
    o.a = __floats2half2_rn(y[0], y[1]);
    o.b = __floats2half2_rn(y[2], y[3]);
    *(h4*)(ys2 + (size_t)node * 32 + c0) = o;
}

// ---------------- prep3 ----------------

__global__ void k_prep3(const float* __restrict__ stats, const float* __restrict__ gamma,
                        const float* __restrict__ beta, const float* __restrict__ W3,
                        __half* __restrict__ wfrag, float* __restrict__ cw3,
                        __half* __restrict__ ys2) {
    __shared__ float a2[32], c2[32];
    int t = threadIdx.x;   // 512
    if (t < 32) {
        float inv_n = 1.0f / (float)N_NODES;
        float m = stats[t] * inv_n;
        float v = stats[32 + t] * inv_n - m * m;
        float a = gamma[t] * rsqrtf(v + BN_EPS);
        a2[t] = a;
        c2[t] = beta[t] - m * a;
    }
    __syncthreads();
    {
        int g = t >> 6, kq = (t >> 4) & 3, c = t & 15;
#pragma unroll
        for (int j = 0; j < 8; ++j) {
            int k = kq * 8 + j;
            wfrag[(size_t)t * 8 + j] = __float2half(a2[k] * W3[k * 128 + g * 16 + c]);
        }
    }
    if (t < 128) {
        float cb = 0.f;
#pragma unroll
        for (int k = 0; k < 32; ++k) cb += c2[k] * W3[k * 128 + t];
        cw3[t] = cb;
    }
    if (t >= 480 && t < 496)
        ((__half2*)(ys2 + (size_t)N_NODES * 32))[t - 480] =
            __half2{__float2half(0.f), __float2half(0.f)};
}

// ---------------- layer 3 aggregation: ys2 (width 32) -> u2 ----------------

__global__ void k_agg3(const __half* __restrict__ ys2, const int* __restrict__ offs,
                       const int* __restrict__ ends, const int* __restrict__ csr,
                       const float* __restrict__ dis, __half* __restrict__ u2) {
    int wave = threadIdx.x >> 6;
    int lane = threadIdx.x & 63;
    int node = blockIdx.x * 4 + wave;
    if (node >= N_NODES) return;
    int chunk = lane & 7;
    int eg = lane >> 3;
    int e0 = offs[node], e1 = ends[node];
    float ax = 0.f, ay = 0.f, az = 0.f, aw = 0.f;
    const __half* hp = ys2 + (size_t)chunk * 4;
    for (int e = e0 + eg; e < e1; e += 32) {
        int s0 = csr[e];
        int s1 = (e + 8 < e1) ? csr[e + 8] : N_NODES;
        int s2 = (e + 16 < e1) ? csr[e + 16] : N_NODES;
        int s3 = (e + 24 < e1) ? csr[e + 24] : N_NODES;
        h4 v0 = *(const h4*)(hp + (size_t)s0 * 32);
        h4 v1 = *(const h4*)(hp + (size_t)s1 * 32);
        h4 v2 = *(const h4*)(hp + (size_t)s2 * 32);
        h4 v3 = *(const h4*)(hp + (size_t)s3 * 32);
        ax += __low2float(v0.a) + __low2float(v1.a) + __low2float(v2.a) + __low2float(v3.a);
        ay += __high2float(v0.a) + __high2float(v1.a) + __high2float(v2.a) + __high2float(v3.a);
        az += __low2float(v0.b) + __low2float(v1.b) + __low2float(v2.b) + __low2float(v3.b);
        aw += __high2float(v0.b) + __high2float(v1.b) + __high2float(v2.b) + __high2float(v3.b);
    }
    if (eg == 0) {
        h4 v = *(const h4*)(hp + (size_t)node * 32);
        ax += __low2float(v.a);
        ay += __high2float(v.a);
        az += __low2float(v.b);
        aw += __high2float(v.b);
    }
#pragma unroll
    for (int off = 8; off < 64; off <<= 1) {
        ax += __shfl_xor(ax, off, 64);
        ay += __shfl_xor(ay, off, 64);
        az += __shfl_xor(az, off, 64);
        aw += __shfl_xor(aw, off, 64);
    }
    if (lane < 8) {
        float dn = dis[node];
        h4 o;
        o.a = __floats2half2_rn(dn * ax, dn * ay);
        o.b = __floats2half2_rn(dn * az, dn * aw);
        *(h4*)(u2 + (size_t)node * 32 + chunk * 4) = o;
    }
}

// ---------------- layer 3 transform via MFMA ----------------

__global__ void k_mm_mfma(const __half* __restrict__ u2, const __half* __restrict__ wfrag,
                          const float* __restrict__ cw3, const float* __restrict__ b3,
                          const float* __restrict__ svec, const float* __restrict__ dis,
                          __half* __restrict__ ys3) {
    int wave = threadIdx.x >> 6;
    int lane = threadIdx.x & 63;
    int n0 = (blockIdx.x * 4 + wave) * 16;
    if (n0 >= N_NODES) return;
    int m = lane & 15;
    int kq = lane >> 4;

    half8_t af = *(const half8_t*)(u2 + (size_t)(n0 + m) * 32 + kq * 8);

    float4_t accs[8];
#pragma unroll
    for (int g = 0; g < 8; ++g) {
        float4_t acc = {0.f, 0.f, 0.f, 0.f};
        half8_t bf = *(const half8_t*)(wfrag + (size_t)((g * 4 + kq) * 16 + m) * 8);
        accs[g] = __builtin_amdgcn_mfma_f32_16x16x32_f16(af, bf, acc, 0, 0, 0);
    }
    float sv[4], dn[4];
#pragma unroll
    for (int r = 0; r < 4; ++r) {
        sv[r] = svec[n0 + kq * 4 + r];
        dn[r] = dis[n0 + kq * 4 + r];
    }
#pragma unroll
    for (int g = 0; g < 8; ++g) {
        float cwf = cw3[g * 16 + m];
        float bf3 = b3[g * 16 + m];
#pragma unroll
        for (int r = 0; r < 4; ++r) {
            float y = fmaxf(accs[g][r] + sv[r] * cwf + bf3, 0.f);
            ys3[(size_t)(n0 + kq * 4 + r) * 128 + g * 16 + m] = __float2half(dn[r] * y);
        }
    }
}

// ---------------- BN stats over y = ys * rdis (small widths: 8/32) ----------------

template <int FOUT>
__global__ void k_stats(const __half* __restrict__ ys, const float* __restrict__ rdis,
                        float* __restrict__ stats) {
    constexpr int GP = 256 / FOUT;
    int f = threadIdx.x % FOUT, g = threadIdx.x / FOUT;
    float s = 0.f, s2 = 0.f;
    for (int n = blockIdx.x * GP + g; n < N_NODES; n += gridDim.x * GP) {
        float v = __half2float(ys[(size_t)n * FOUT + f]) * rdis[n];
        s += v;
        s2 += v * v;
    }
    __shared__ float ls[256], ls2[256];
    ls[threadIdx.x] = s;
    ls2[threadIdx.x] = s2;
    __syncthreads();
    if (g == 0) {
        for (int gg = 1; gg < GP; ++gg) {
            s += ls[gg * FOUT + f];
            s2 += ls2[gg * FOUT + f];
        }
        atomicAdd(&stats[f], s);
        atomicAdd(&stats[FOUT + f], s2);
    }
}

// ---------------- BN stats width 128: two-phase vectorized ----------------

__global__ void k_stats128(const __half* __restrict__ ys, const float* __restrict__ rdis,
                           float* __restrict__ part) {
    int t = threadIdx.x;
    int chunk = t & 15, row = t >> 4;
    int n0 = blockIdx.x * 128;
    float s[8] = {0, 0, 0, 0, 0, 0, 0, 0};
    float s2[8] = {0, 0, 0, 0, 0, 0, 0, 0};
#pragma unroll
    for (int i = 0; i < 8; ++i) {
        int n = n0 + i * 16 + row;
        if (n < N_NODES) {
            float r = rdis[n];
            h8s v = *(const h8s*)(ys + (size_t)n * 128 + chunk * 8);
#pragma unroll
            for (int q = 0; q < 4; ++q) {
                float v0 = __low2float(v.h[q]) * r;
                float v1 = __high2float(v.h[q]) * r;
                s[2 * q] += v0;  s2[2 * q] += v0 * v0;
                s[2 * q + 1] += v1;  s2[2 * q + 1] += v1 * v1;
            }
        }
    }
#pragma unroll
    for (int off = 16; off < 64; off <<= 1)
#pragma unroll
        for (int j = 0; j < 8; ++j) {
            s[j] += __shfl_xor(s[j], off, 64);
            s2[j] += __shfl_xor(s2[j], off, 64);
        }
    __shared__ float sm[256];
    sm[t] = 0.f;
    __syncthreads();
    if ((t & 63) < 16) {
#pragma unroll
        for (int j = 0; j < 8; ++j) {
            atomicAdd(&sm[chunk * 8 + j], s[j]);
            atomicAdd(&sm[128 + chunk * 8 + j], s2[j]);
        }
    }
    __syncthreads();
    part[(size_t)blockIdx.x * 256 + t] = sm[t];
}

__global__ void k_stats_red(const float* __restrict__ part, float* __restrict__ stats) {
    int i = blockIdx.x;   // 0..255
    int t = threadIdx.x;  // 256
    float s = 0.f;
    for (int b = t; b < NSTATB; b += 256) s += part[(size_t)b * 256 + i];
    __shared__ float sm[256];
    sm[t] = s;
    __syncthreads();
    for (int st = 128; st > 0; st >>= 1) {
        if (t < st) sm[t] += sm[t + st];
        __syncthreads();
    }
    if (t == 0) stats[i] = sm[0];
}

// ---------------- pooling: segment-parallel max/min ----------------

__global__ void k_pool1(const __half* __restrict__ ys3, const float* __restrict__ rdis,
                        const int* __restrict__ batch, int* __restrict__ gmax,
                        int* __restrict__ gmin) {
    __shared__ int sb[LSEG];
    __shared__ float sr[LSEG];
    int n0 = blockIdx.x * LSEG;
    int n1 = min(n0 + LSEG, N_NODES);
    int L = n1 - n0;
    int f = threadIdx.x;    // 128 threads = feature
    for (int i = f; i < L; i += 128) { sb[i] = batch[n0 + i]; sr[i] = rdis[n0 + i]; }
    __syncthreads();
    if (L <= 0) return;
    int cg = sb[0];
    int mx = 0;
    int mn = 0x7F800000;
    for (int i = 0; i < L; ++i) {
        int g = sb[i];
        if (g != cg) {
            atomicMax(&gmax[cg * 128 + f], mx);
            atomicMin(&gmin[cg * 128 + f], mn);
            cg = g; mx = 0; mn = 0x7F800000;
        }
        float v = __half2float(ys3[(size_t)(n0 + i) * 128 + f]) * sr[i];
        int b = __float_as_int(v);
        mx = max(mx, b);
        mn = min(mn, b);
    }
    atomicMax(&gmax[cg * 128 + f], mx);
    atomicMin(&gmin[cg * 128 + f], mn);
}

// ---------------- fused bn-affine + head + log_softmax ----------------

__device__ __forceinline__ int lower_bound_dev(const int* __restrict__ a, int val) {
    int lo = 0, hi = N_NODES;
    while (lo < hi) {
        int mid = (lo + hi) >> 1;
        if (a[mid] < val) lo = mid + 1; else hi = mid;
    }
    return lo;
}

__global__ void k_poolhead(const int* __restrict__ gmax, const int* __restrict__ gmin,
                           const int* __restrict__ batch, const float* __restrict__ stats,
                           const float* __restrict__ gamma, const float* __restrict__ beta,
                           const float* __restrict__ Wl, const float* __restrict__ bl,
                           float* __restrict__ out) {
    int g = blockIdx.x;
    int f = threadIdx.x;    // 128
    float inv_n = 1.0f / (float)N_NODES;
    float m = stats[f] * inv_n;
    float var = stats[128 + f] * inv_n - m * m;
    float a = gamma[f] * rsqrtf(var + BN_EPS);
    float c = beta[f] - m * a;
    int s = lower_bound_dev(batch, g);
    int e = lower_bound_dev(batch, g + 1);
    float mx = __int_as_float(gmax[g * 128 + f]);
    float mn = __int_as_float(gmin[g * 128 + f]);
    float r;
    if (e > s) r = (a >= 0.f) ? (a * mx + c) : (a * mn + c);
    else r = -INFINITY;
    __shared__ float l[3][128];
    l[0][f] = r * Wl[f * 3 + 0];
    l[1][f] = r * Wl[f * 3 + 1];
    l[2][f] = r * Wl[f * 3 + 2];
    __syncthreads();
    for (int st = 64; st > 0; st >>= 1) {
        if (f < st) {
            l[0][f] += l[0][f + st];
            l[1][f] += l[1][f + st];
            l[2][f] += l[2][f + st];
        }
        __syncthreads();
    }
    if (f == 0) {
        float l0 = l[0][0] + bl[0], l1 = l[1][0] + bl[1], l2 = l[2][0] + bl[2];
        float mxl = fmaxf(l0, fmaxf(l1, l2));
        float lse = mxl + logf(expf(l0 - mxl) + expf(l1 - mxl) + expf(l2 - mxl));
        out[g * 3 + 0] = l0 - lse;
        out[g * 3 + 1] = l1 - lse;
        out[g * 3 + 2] = l2 - lse;
    }
}

// ---------------- launch ----------------

extern "C" void kernel_launch(void* const* d_in, const int* in_sizes, int n_in,
                              void* d_out, int out_size, void* d_ws, size_t ws_size,
                              hipStream_t stream) {
    const float* x   = (const float*)d_in[0];
    const int* ei    = (const int*)d_in[1];
    const int* src   = ei;
    const int* dst   = ei + N_EDGES;
    const int* batch = (const int*)d_in[2];
    const float *W1 = (const float*)d_in[3],  *b1 = (const float*)d_in[4];
    const float *g1 = (const float*)d_in[5],  *be1 = (const float*)d_in[6];
    const float *W2 = (const float*)d_in[7],  *b2 = (const float*)d_in[8];
    const float *g2 = (const float*)d_in[9],  *be2 = (const float*)d_in[10];
    const float *W3 = (const float*)d_in[11], *b3 = (const float*)d_in[12];
    const float *g3 = (const float*)d_in[13], *be3 = (const float*)d_in[14];
    const float *Wl = (const float*)d_in[15], *bl = (const float*)d_in[16];
    float* out = (float*)d_out;

    // workspace carve (4-byte words)
    int* base = (int*)d_ws;
    size_t o = 0;
    float* stats1 = (float*)(base + o); o += 256;
    float* stats2 = (float*)(base + o); o += 256;
    float* stats3 = (float*)(base + o); o += 256;
    int* gmax     = base + o; o += (size_t)N_GRAPHS * 128;
    size_t zero_words = o;                         // zeroed region
    int* gmin     = base + o; o += (size_t)N_GRAPHS * 128;   // memset 0x7F
    int* bbase    = base + o; o += 392;
    int* ghist    = base + o; o += 392;
    int* hists    = base + o; o += ((size_t)NBIN * NCHUNK + 3) & ~3ULL;
    float* W2p    = (float*)(base + o); o += 256;
    float* cw2    = (float*)(base + o); o += 32;
    __half* wfrag = (__half*)(base + o); o += 2048;
    float* cw3    = (float*)(base + o); o += 128;
    int* offs     = base + o; o += 100000;
    int* ends     = base + o; o += 100000;
    int* store    = base + o; o += STORE_CAP;
    int* csr      = base + o; o += STORE_CAP;
    float* dis    = (float*)(base + o); o += N_NODES;
    float* rdis   = (float*)(base + o); o += N_NODES;
    float* svec   = (float*)(base + o); o += N_NODES;
    float* spart  = (float*)(base + o); o += (size_t)NSTATB * 256;
    float4* xd    = (float4*)(base + o); o += (size_t)(N_NODES + 1) * 4;
    __half* ys1   = (__half*)(base + o); o += (size_t)(N_NODES + 1) * 4;
    __half* ys2   = (__half*)(base + o); o += (size_t)(N_NODES + 1) * 16;
    __half* u2    = (__half*)(base + o); o += (size_t)N_NODES * 16;
    __half* ys3   = (__half*)(base + o); o += (size_t)N_NODES * 64;
    if (ws_size < o * 4) return;

    const int TB = 256;

    hipMemsetAsync(base, 0, zero_words * 4, stream);
    hipMemsetAsync(gmin, 0x7F, (size_t)N_GRAPHS * 128 * 4, stream);

    // CSR build (padded radix, LDS-staged scatter)
    k_hist2<<<NCHUNK, TB, 0, stream>>>(dst, hists);
    k_scan2<<<NBIN, 64, 0, stream>>>(hists, ghist);
    k_binscan<<<1, 512, 0, stream>>>(ghist, bbase);
    k_scatter<<<NCHUNK, TB, 0, stream>>>(src, dst, bbase, hists, store);
    k_csr_build<<<NBIN, 256, 0, stream>>>(bbase, store, x, offs, ends, dis, rdis, xd, csr);

    // layer 1 (4 nodes/wave, 16 nodes/block)
    k_agg1<<<N_NODES / 16, TB, 0, stream>>>(xd, offs, ends, csr, W1, b1, svec, ys1);
    k_stats<8><<<256, 256, 0, stream>>>(ys1, rdis, stats1);
    k_prep2<<<1, 256, 0, stream>>>(stats1, g1, be1, W2, W2p, cw2, ys1);

    // layer 2 (8 nodes/wave, 32 nodes/block)
    k_agg2<<<N_NODES / 32, TB, 0, stream>>>(ys1, offs, ends, csr, dis, svec, W2p, cw2, b2, ys2);
    k_stats<32><<<256, 256, 0, stream>>>(ys2, rdis, stats2);
    k_prep3<<<1, 512, 0, stream>>>(stats2, g2, be2, W3, wfrag, cw3, ys2);

    // layer 3
    k_agg3<<<(N_NODES + 3) / 4, TB, 0, stream>>>(ys2, offs, ends, csr, dis, u2);
    k_mm_mfma<<<(N_NODES + 63) / 64, 256, 0, stream>>>(u2, wfrag, cw3, b3, svec, dis, ys3);
    k_stats128<<<NSTATB, 256, 0, stream>>>(ys3, rdis, spart);
    k_stats_red<<<256, 256, 0, stream>>>(spart, stats3);

    // pool + head
    k_pool1<<<NSEGB, 128, 0, stream>>>(ys3, rdis, batch, gmax, gmin);
    k_poolhead<<<N_GRAPHS, 128, 0, stream>>>(gmax, gmin, batch, stats3, g3, be3, Wl, bl, out);
}

// Round 14
// 399.328 us; speedup vs baseline: 1.0339x; 1.0339x over previous
//
#include <hip/hip_runtime.h>
#include <hip/hip_bf16.h>
#include <hip/hip_fp16.h>
#include <math.h>

#define N_NODES 100000
#define N_EDGES 3200000
#define N_GRAPHS 512
#define BN_EPS 1e-5f
#define NBIN ((N_NODES + 511) / 512)            // 196 bins of 512 nodes
#define CHUNK 8192                              // edges per chunk
#define NCHUNK ((N_EDGES + CHUNK - 1) / CHUNK)  // 391
#define STORE_CAP (N_EDGES + 16 * NBIN * NCHUNK)  // padded store capacity
#define LSEG 98
#define NSEGB ((N_NODES + LSEG - 1) / LSEG)     // 1021 pool segments
#define NSTATB ((N_NODES + 127) / 128)          // 782 stats slabs

typedef _Float16 half8_t __attribute__((ext_vector_type(8)));
typedef float float4_t __attribute__((ext_vector_type(4)));

struct alignas(8) h4 { __half2 a, b; };
struct alignas(16) h8s { __half2 h[4]; };

// ---------------- CSR build: padded single-scatter radix, 512-node bins ----------------

__global__ void k_hist2(const int* __restrict__ dst, int* __restrict__ hists) {
    __shared__ int h[NBIN];
    for (int i = threadIdx.x; i < NBIN; i += blockDim.x) h[i] = 0;
    __syncthreads();
    int e0 = blockIdx.x * CHUNK;
    int e1 = min(e0 + CHUNK, N_EDGES);
    for (int e = e0 + threadIdx.x; e < e1; e += blockDim.x)
        atomicAdd(&h[dst[e] >> 9], 1);
    __syncthreads();
    for (int i = threadIdx.x; i < NBIN; i += blockDim.x)
        hists[i * NCHUNK + blockIdx.x] = h[i];
}

// per-bin exclusive scan over chunks of PADDED counts (pad to x16 -> 64B runs)
__global__ void k_scan2(int* __restrict__ hists, int* __restrict__ ghist) {
    int b = blockIdx.x;
    int lane = threadIdx.x;   // 64 threads
    int carry = 0;
    int base = b * NCHUNK;
    for (int c0 = 0; c0 < NCHUNK; c0 += 64) {
        int c = c0 + lane;
        int v = (c < NCHUNK) ? hists[base + c] : 0;
        int pv = (v + 15) & ~15;
        int inc = pv;
#pragma unroll
        for (int off = 1; off < 64; off <<= 1) {
            int u = __shfl_up(inc, off, 64);
            if (lane >= off) inc += u;
        }
        if (c < NCHUNK) hists[base + c] = inc - pv + carry;
        carry += __shfl(inc, 63, 64);
    }
    if (lane == 0) ghist[b] = carry;   // padded bin total
}

__global__ void k_binscan(const int* __restrict__ ghist, int* __restrict__ bbase) {
    __shared__ int sd[512];
    int t = threadIdx.x;
    int v = (t < NBIN) ? ghist[t] : 0;
    sd[t] = v;
    __syncthreads();
    for (int off = 1; off < 512; off <<= 1) {
        int u = (t >= off) ? sd[t - off] : 0;
        __syncthreads();
        sd[t] += u;
        __syncthreads();
    }
    if (t < NBIN) bbase[t] = sd[t] - v;
    if (t == 511) bbase[NBIN] = sd[511];   // padded grand total
}

// per-chunk direct scatter (391 blocks) + sentinel pad to 64B run boundaries
__global__ void k_scatter(const int* __restrict__ src, const int* __restrict__ dst,
                          const int* __restrict__ bbase, const int* __restrict__ hists,
                          int* __restrict__ store) {
    __shared__ int cur[NBIN];
    for (int i = threadIdx.x; i < NBIN; i += blockDim.x)
        cur[i] = bbase[i] + hists[i * NCHUNK + blockIdx.x];
    __syncthreads();
    int e0 = blockIdx.x * CHUNK;
    int e1 = min(e0 + CHUNK, N_EDGES);
    for (int e = e0 + threadIdx.x; e < e1; e += blockDim.x) {
        int d = dst[e];
        int b = d >> 9;
        int pos = atomicAdd(&cur[b], 1);
        store[pos] = (src[e] << 9) | (d & 511);
    }
    __syncthreads();
    // pad each run's tail to the 16-slot boundary -> every line fully written
    for (int i = threadIdx.x; i < NBIN; i += blockDim.x) {
        int p = cur[i];
        int end = (p + 15) & ~15;
        for (; p < end; ++p) store[p] = -1;
    }
}

__global__ void k_csr_build(const int* __restrict__ bbase, const int* __restrict__ store,
                            const float* __restrict__ x, int* __restrict__ offs,
                            int* __restrict__ ends, float* __restrict__ dis,
                            float* __restrict__ rdis, float4* __restrict__ xd,
                            int* __restrict__ csr) {
    __shared__ int cnt[512], cur[512], wsum[4];
    int b = blockIdx.x;
    int n0 = b << 9;
    int e0 = bbase[b], e1 = bbase[b + 1];
    int t = threadIdx.x;
    int lane = t & 63, wid = t >> 6;
    cnt[t] = 0;
    cnt[t + 256] = 0;
    __syncthreads();
    for (int e = e0 + t; e < e1; e += 256) {
        int p = store[e];
        if (p >= 0) atomicAdd(&cnt[p & 511], 1);
    }
    __syncthreads();
    // scan 512 counts: thread t owns entries 2t, 2t+1
    int c0 = cnt[2 * t], c1 = cnt[2 * t + 1];
    int pair = c0 + c1;
    int inc = pair;
#pragma unroll
    for (int off = 1; off < 64; off <<= 1) {
        int u = __shfl_up(inc, off, 64);
        if (lane >= off) inc += u;
    }
    if (lane == 63) wsum[wid] = inc;
    __syncthreads();
    int wo = 0;
    for (int w = 0; w < wid; ++w) wo += wsum[w];
    int ex = inc - pair + wo;
    cur[2 * t] = ex;
    cur[2 * t + 1] = ex + c0;
#pragma unroll
    for (int j = 0; j < 2; ++j) {
        int n = n0 + 2 * t + j;
        int cc = j ? c1 : c0;
        int exx = j ? ex + c0 : ex;
        if (n < N_NODES) {
            offs[n] = e0 + exx;
            ends[n] = e0 + exx + cc;
            float dn = rsqrtf(1.0f + (float)cc);
            dis[n] = dn;
            rdis[n] = sqrtf(1.0f + (float)cc);
            float2 xv = *(const float2*)(x + 2 * (size_t)n);
            xd[n] = make_float4(dn * xv.x, dn * xv.y, dn, 0.f);
        } else if (n == N_NODES) {
            xd[N_NODES] = make_float4(0.f, 0.f, 0.f, 0.f);
        }
    }
    __syncthreads();
    for (int e = e0 + t; e < e1; e += 256) {
        int p = store[e];
        if (p >= 0) {
            int pos = e0 + atomicAdd(&cur[p & 511], 1);
            csr[pos] = p >> 9;
        }
    }
}

// ---------------- layer 1: 4 nodes/wave, aggregate xd + fused 2->8 mm + relu ----------------

__global__ void k_agg1(const float4* __restrict__ xd, const int* __restrict__ offs,
                       const int* __restrict__ ends, const int* __restrict__ csr,
                       const float* __restrict__ W1, const float* __restrict__ b1,
                       float* __restrict__ svec, __half* __restrict__ ys1) {
    __shared__ float sW[16], sb[8];
    int t = threadIdx.x;
    if (t < 16) sW[t] = W1[t];
    if (t < 8) sb[t] = b1[t];
    __syncthreads();
    int wave = t >> 6, lane = t & 63;
    int nsub = lane >> 4, eg = lane & 15;
    int node = ((blockIdx.x * 4 + wave) << 2) + nsub;   // exact: 100000 = 25000*4
    int e0 = offs[node], e1 = ends[node];
    float ax = 0.f, ay = 0.f, as = 0.f;
    for (int e = e0 + eg; e < e1; e += 32) {
        int s0 = csr[e];
        int s1 = (e + 16 < e1) ? csr[e + 16] : N_NODES;
        float4 v0 = xd[s0];
        float4 v1 = xd[s1];
        ax += v0.x + v1.x;
        ay += v0.y + v1.y;
        as += v0.z + v1.z;
    }
#pragma unroll
    for (int off = 1; off < 16; off <<= 1) {
        ax += __shfl_xor(ax, off, 64);
        ay += __shfl_xor(ay, off, 64);
        as += __shfl_xor(as, off, 64);
    }
    if (eg == 0) {
        float4 xn = xd[node];
        float dn = xn.z;
        float u0x = dn * (ax + xn.x);
        float u0y = dn * (ay + xn.y);
        svec[node] = dn * (as + xn.z);
        float y[8];
#pragma unroll
        for (int f = 0; f < 8; ++f)
            y[f] = dn * fmaxf(u0x * sW[f] + u0y * sW[8 + f] + sb[f], 0.f);
        h8s o;
#pragma unroll
        for (int q = 0; q < 4; ++q) o.h[q] = __floats2half2_rn(y[2 * q], y[2 * q + 1]);
        *(h8s*)(ys1 + (size_t)node * 8) = o;
    }
}

// ---------------- prep2: bn fold into W2; zero row ys1[N] ----------------

__global__ void k_prep2(const float* __restrict__ stats, const float* __restrict__ gamma,
                        const float* __restrict__ beta, const float* __restrict__ W2,
                        float* __restrict__ W2p, float* __restrict__ cw2,
                        __half* __restrict__ ys1) {
    __shared__ float a1[8], c1[8];
    int t = threadIdx.x;   // 256
    if (t < 8) {
        float inv_n = 1.0f / (float)N_NODES;
        float m = stats[t] * inv_n;
        float v = stats[8 + t] * inv_n - m * m;
        float a = gamma[t] * rsqrtf(v + BN_EPS);
        a1[t] = a;
        c1[t] = beta[t] - m * a;
    }
    __syncthreads();
    W2p[t] = a1[t >> 5] * W2[t];    // 8x32 = 256
    if (t < 32) {
        float cb = 0.f;
#pragma unroll
        for (int i = 0; i < 8; ++i) cb += c1[i] * W2[i * 32 + t];
        cw2[t] = cb;
    }
    if (t == 128) *(int4*)(ys1 + (size_t)N_NODES * 8) = make_int4(0, 0, 0, 0);
}

// ---------------- layer 2: 8 nodes/wave, aggregate ys1 (width 8) + fused 8->32 mm ----------------

__global__ void k_agg2(const __half* __restrict__ ys1, const int* __restrict__ offs,
                       const int* __restrict__ ends, const int* __restrict__ csr,
                       const float* __restrict__ dis, const float* __restrict__ svec,
                       const float* __restrict__ W2p, const float* __restrict__ cw2,
                       const float* __restrict__ b2, __half* __restrict__ ys2) {
    __shared__ float sW[256], sC[32], sB[32];
    int t = threadIdx.x;
    sW[t] = W2p[t];
    if (t < 32) { sC[t] = cw2[t]; sB[t] = b2[t]; }
    __syncthreads();
    int wave = t >> 6, lane = t & 63;
    int nsub = lane >> 3, eg = (lane >> 1) & 3, chunk = lane & 1;
    int node = ((blockIdx.x * 4 + wave) << 3) + nsub;   // exact: 100000 = 12500*8
    int e0 = offs[node], e1 = ends[node];
    float a0 = 0.f, a1 = 0.f, a2 = 0.f, a3 = 0.f;
    const __half* hp = ys1 + chunk * 4;
    for (int e = e0 + eg; e < e1; e += 8) {
        int s0 = csr[e];
        int s1 = (e + 4 < e1) ? csr[e + 4] : N_NODES;
        h4 v0 = *(const h4*)(hp + (size_t)s0 * 8);
        h4 v1 = *(const h4*)(hp + (size_t)s1 * 8);
        a0 += __low2float(v0.a) + __low2float(v1.a);
        a1 += __high2float(v0.a) + __high2float(v1.a);
        a2 += __low2float(v0.b) + __low2float(v1.b);
        a3 += __high2float(v0.b) + __high2float(v1.b);
    }
    if (eg == 0) {   // self-loop
        h4 v = *(const h4*)(hp + (size_t)node * 8);
        a0 += __low2float(v.a);
        a1 += __high2float(v.a);
        a2 += __low2float(v.b);
        a3 += __high2float(v.b);
    }
#pragma unroll
    for (int off = 2; off < 8; off <<= 1) {
        a0 += __shfl_xor(a0, off, 64);
        a1 += __shfl_xor(a1, off, 64);
        a2 += __shfl_xor(a2, off, 64);
        a3 += __shfl_xor(a3, off, 64);
    }
    int lb = nsub << 3;
    float u[8];
    u[0] = __shfl(a0, lb, 64);     u[1] = __shfl(a1, lb, 64);
    u[2] = __shfl(a2, lb, 64);     u[3] = __shfl(a3, lb, 64);
    u[4] = __shfl(a0, lb + 1, 64); u[5] = __shfl(a1, lb + 1, 64);
    u[6] = __shfl(a2, lb + 1, 64); u[7] = __shfl(a3, lb + 1, 64);
    float dn = dis[node];
    float sv = svec[node];
#pragma unroll
    for (int i = 0; i < 8; ++i) u[i] *= dn;
    int c0 = (lane & 7) * 4;
    float y[4];
#pragma unroll
    for (int k = 0; k < 4; ++k) {
        int col = c0 + k;
        float conv = sB[col] + sv * sC[col];
#pragma unroll
        for (int i = 0; i < 8; ++i) conv += u[i] * sW[i * 32 + col];
        y[k] = dn * fmaxf(conv, 0.f);
    }
    h4 o;
    o.a = __floats2half2_rn(y[0], y[1]);
    o.b = __floats2half2_rn(y[2], y[3]);
    *(h4*)(ys2 + (size_t)node * 32 + c0) = o;
}

// ---------------- prep3 ----------------

__global__ void k_prep3(const float* __restrict__ stats, const float* __restrict__ gamma,
                        const float* __restrict__ beta, const float* __restrict__ W3,
                        __half* __restrict__ wfrag, float* __restrict__ cw3,
                        __half* __restrict__ ys2) {
    __shared__ float a2[32], c2[32];
    int t = threadIdx.x;   // 512
    if (t < 32) {
        float inv_n = 1.0f / (float)N_NODES;
        float m = stats[t] * inv_n;
        float v = stats[32 + t] * inv_n - m * m;
        float a = gamma[t] * rsqrtf(v + BN_EPS);
        a2[t] = a;
        c2[t] = beta[t] - m * a;
    }
    __syncthreads();
    {
        int g = t >> 6, kq = (t >> 4) & 3, c = t & 15;
#pragma unroll
        for (int j = 0; j < 8; ++j) {
            int k = kq * 8 + j;
            wfrag[(size_t)t * 8 + j] = __float2half(a2[k] * W3[k * 128 + g * 16 + c]);
        }
    }
    if (t < 128) {
        float cb = 0.f;
#pragma unroll
        for (int k = 0; k < 32; ++k) cb += c2[k] * W3[k * 128 + t];
        cw3[t] = cb;
    }
    if (t >= 480 && t < 496)
        ((__half2*)(ys2 + (size_t)N_NODES * 32))[t - 480] =
            __half2{__float2half(0.f), __float2half(0.f)};
}

// ---------------- layer 3 aggregation: ys2 (width 32) -> u2 ----------------

__global__ void k_agg3(const __half* __restrict__ ys2, const int* __restrict__ offs,
                       const int* __restrict__ ends, const int* __restrict__ csr,
                       const float* __restrict__ dis, __half* __restrict__ u2) {
    int wave = threadIdx.x >> 6;
    int lane = threadIdx.x & 63;
    int node = blockIdx.x * 4 + wave;
    if (node >= N_NODES) return;
    int chunk = lane & 7;
    int eg = lane >> 3;
    int e0 = offs[node], e1 = ends[node];
    float ax = 0.f, ay = 0.f, az = 0.f, aw = 0.f;
    const __half* hp = ys2 + (size_t)chunk * 4;
    for (int e = e0 + eg; e < e1; e += 32) {
        int s0 = csr[e];
        int s1 = (e + 8 < e1) ? csr[e + 8] : N_NODES;
        int s2 = (e + 16 < e1) ? csr[e + 16] : N_NODES;
        int s3 = (e + 24 < e1) ? csr[e + 24] : N_NODES;
        h4 v0 = *(const h4*)(hp + (size_t)s0 * 32);
        h4 v1 = *(const h4*)(hp + (size_t)s1 * 32);
        h4 v2 = *(const h4*)(hp + (size_t)s2 * 32);
        h4 v3 = *(const h4*)(hp + (size_t)s3 * 32);
        ax += __low2float(v0.a) + __low2float(v1.a) + __low2float(v2.a) + __low2float(v3.a);
        ay += __high2float(v0.a) + __high2float(v1.a) + __high2float(v2.a) + __high2float(v3.a);
        az += __low2float(v0.b) + __low2float(v1.b) + __low2float(v2.b) + __low2float(v3.b);
        aw += __high2float(v0.b) + __high2float(v1.b) + __high2float(v2.b) + __high2float(v3.b);
    }
    if (eg == 0) {
        h4 v = *(const h4*)(hp + (size_t)node * 32);
        ax += __low2float(v.a);
        ay += __high2float(v.a);
        az += __low2float(v.b);
        aw += __high2float(v.b);
    }
#pragma unroll
    for (int off = 8; off < 64; off <<= 1) {
        ax += __shfl_xor(ax, off, 64);
        ay += __shfl_xor(ay, off, 64);
        az += __shfl_xor(az, off, 64);
        aw += __shfl_xor(aw, off, 64);
    }
    if (lane < 8) {
        float dn = dis[node];
        h4 o;
        o.a = __floats2half2_rn(dn * ax, dn * ay);
        o.b = __floats2half2_rn(dn * az, dn * aw);
        *(h4*)(u2 + (size_t)node * 32 + chunk * 4) = o;
    }
}

// ---------------- layer 3 transform via MFMA ----------------

__global__ void k_mm_mfma(const __half* __restrict__ u2, const __half* __restrict__ wfrag,
                          const float* __restrict__ cw3, const float* __restrict__ b3,
                          const float* __restrict__ svec, const float* __restrict__ dis,
                          __half* __restrict__ ys3) {
    int wave = threadIdx.x >> 6;
    int lane = threadIdx.x & 63;
    int n0 = (blockIdx.x * 4 + wave) * 16;
    if (n0 >= N_NODES) return;
    int m = lane & 15;
    int kq = lane >> 4;

    half8_t af = *(const half8_t*)(u2 + (size_t)(n0 + m) * 32 + kq * 8);

    float4_t accs[8];
#pragma unroll
    for (int g = 0; g < 8; ++g) {
        float4_t acc = {0.f, 0.f, 0.f, 0.f};
        half8_t bf = *(const half8_t*)(wfrag + (size_t)((g * 4 + kq) * 16 + m) * 8);
        accs[g] = __builtin_amdgcn_mfma_f32_16x16x32_f16(af, bf, acc, 0, 0, 0);
    }
    float sv[4], dn[4];
#pragma unroll
    for (int r = 0; r < 4; ++r) {
        sv[r] = svec[n0 + kq * 4 + r];
        dn[r] = dis[n0 + kq * 4 + r];
    }
#pragma unroll
    for (int g = 0; g < 8; ++g) {
        float cwf = cw3[g * 16 + m];
        float bf3 = b3[g * 16 + m];
#pragma unroll
        for (int r = 0; r < 4; ++r) {
            float y = fmaxf(accs[g][r] + sv[r] * cwf + bf3, 0.f);
            ys3[(size_t)(n0 + kq * 4 + r) * 128 + g * 16 + m] = __float2half(dn[r] * y);
        }
    }
}

// ---------------- BN stats over y = ys * rdis (small widths: 8/32) ----------------

template <int FOUT>
__global__ void k_stats(const __half* __restrict__ ys, const float* __restrict__ rdis,
                        float* __restrict__ stats) {
    constexpr int GP = 256 / FOUT;
    int f = threadIdx.x % FOUT, g = threadIdx.x / FOUT;
    float s = 0.f, s2 = 0.f;
    for (int n = blockIdx.x * GP + g; n < N_NODES; n += gridDim.x * GP) {
        float v = __half2float(ys[(size_t)n * FOUT + f]) * rdis[n];
        s += v;
        s2 += v * v;
    }
    __shared__ float ls[256], ls2[256];
    ls[threadIdx.x] = s;
    ls2[threadIdx.x] = s2;
    __syncthreads();
    if (g == 0) {
        for (int gg = 1; gg < GP; ++gg) {
            s += ls[gg * FOUT + f];
            s2 += ls2[gg * FOUT + f];
        }
        atomicAdd(&stats[f], s);
        atomicAdd(&stats[FOUT + f], s2);
    }
}

// ---------------- BN stats width 128: two-phase vectorized ----------------

__global__ void k_stats128(const __half* __restrict__ ys, const float* __restrict__ rdis,
                           float* __restrict__ part) {
    int t = threadIdx.x;
    int chunk = t & 15, row = t >> 4;
    int n0 = blockIdx.x * 128;
    float s[8] = {0, 0, 0, 0, 0, 0, 0, 0};
    float s2[8] = {0, 0, 0, 0, 0, 0, 0, 0};
#pragma unroll
    for (int i = 0; i < 8; ++i) {
        int n = n0 + i * 16 + row;
        if (n < N_NODES) {
            float r = rdis[n];
            h8s v = *(const h8s*)(ys + (size_t)n * 128 + chunk * 8);
#pragma unroll
            for (int q = 0; q < 4; ++q) {
                float v0 = __low2float(v.h[q]) * r;
                float v1 = __high2float(v.h[q]) * r;
                s[2 * q] += v0;  s2[2 * q] += v0 * v0;
                s[2 * q + 1] += v1;  s2[2 * q + 1] += v1 * v1;
            }
        }
    }
#pragma unroll
    for (int off = 16; off < 64; off <<= 1)
#pragma unroll
        for (int j = 0; j < 8; ++j) {
            s[j] += __shfl_xor(s[j], off, 64);
            s2[j] += __shfl_xor(s2[j], off, 64);
        }
    __shared__ float sm[256];
    sm[t] = 0.f;
    __syncthreads();
    if ((t & 63) < 16) {
#pragma unroll
        for (int j = 0; j < 8; ++j) {
            atomicAdd(&sm[chunk * 8 + j], s[j]);
            atomicAdd(&sm[128 + chunk * 8 + j], s2[j]);
        }
    }
    __syncthreads();
    part[(size_t)blockIdx.x * 256 + t] = sm[t];
}

__global__ void k_stats_red(const float* __restrict__ part, float* __restrict__ stats) {
    int i = blockIdx.x;   // 0..255
    int t = threadIdx.x;  // 256
    float s = 0.f;
    for (int b = t; b < NSTATB; b += 256) s += part[(size_t)b * 256 + i];
    __shared__ float sm[256];
    sm[t] = s;
    __syncthreads();
    for (int st = 128; st > 0; st >>= 1) {
        if (t < st) sm[t] += sm[t + st];
        __syncthreads();
    }
    if (t == 0) stats[i] = sm[0];
}

// ---------------- pooling: segment-parallel max/min ----------------

__global__ void k_pool1(const __half* __restrict__ ys3, const float* __restrict__ rdis,
                        const int* __restrict__ batch, int* __restrict__ gmax,
                        int* __restrict__ gmin) {
    __shared__ int sb[LSEG];
    __shared__ float sr[LSEG];
    int n0 = blockIdx.x * LSEG;
    int n1 = min(n0 + LSEG, N_NODES);
    int L = n1 - n0;
    int f = threadIdx.x;    // 128 threads = feature
    for (int i = f; i < L; i += 128) { sb[i] = batch[n0 + i]; sr[i] = rdis[n0 + i]; }
    __syncthreads();
    if (L <= 0) return;
    int cg = sb[0];
    int mx = 0;
    int mn = 0x7F800000;
    for (int i = 0; i < L; ++i) {
        int g = sb[i];
        if (g != cg) {
            atomicMax(&gmax[cg * 128 + f], mx);
            atomicMin(&gmin[cg * 128 + f], mn);
            cg = g; mx = 0; mn = 0x7F800000;
        }
        float v = __half2float(ys3[(size_t)(n0 + i) * 128 + f]) * sr[i];
        int b = __float_as_int(v);
        mx = max(mx, b);
        mn = min(mn, b);
    }
    atomicMax(&gmax[cg * 128 + f], mx);
    atomicMin(&gmin[cg * 128 + f], mn);
}

// ---------------- fused bn-affine + head + log_softmax ----------------

__device__ __forceinline__ int lower_bound_dev(const int* __restrict__ a, int val) {
    int lo = 0, hi = N_NODES;
    while (lo < hi) {
        int mid = (lo + hi) >> 1;
        if (a[mid] < val) lo = mid + 1; else hi = mid;
    }
    return lo;
}

__global__ void k_poolhead(const int* __restrict__ gmax, const int* __restrict__ gmin,
                           const int* __restrict__ batch, const float* __restrict__ stats,
                           const float* __restrict__ gamma, const float* __restrict__ beta,
                           const float* __restrict__ Wl, const float* __restrict__ bl,
                           float* __restrict__ out) {
    int g = blockIdx.x;
    int f = threadIdx.x;    // 128
    float inv_n = 1.0f / (float)N_NODES;
    float m = stats[f] * inv_n;
    float var = stats[128 + f] * inv_n - m * m;
    float a = gamma[f] * rsqrtf(var + BN_EPS);
    float c = beta[f] - m * a;
    int s = lower_bound_dev(batch, g);
    int e = lower_bound_dev(batch, g + 1);
    float mx = __int_as_float(gmax[g * 128 + f]);
    float mn = __int_as_float(gmin[g * 128 + f]);
    float r;
    if (e > s) r = (a >= 0.f) ? (a * mx + c) : (a * mn + c);
    else r = -INFINITY;
    __shared__ float l[3][128];
    l[0][f] = r * Wl[f * 3 + 0];
    l[1][f] = r * Wl[f * 3 + 1];
    l[2][f] = r * Wl[f * 3 + 2];
    __syncthreads();
    for (int st = 64; st > 0; st >>= 1) {
        if (f < st) {
            l[0][f] += l[0][f + st];
            l[1][f] += l[1][f + st];
            l[2][f] += l[2][f + st];
        }
        __syncthreads();
    }
    if (f == 0) {
        float l0 = l[0][0] + bl[0], l1 = l[1][0] + bl[1], l2 = l[2][0] + bl[2];
        float mxl = fmaxf(l0, fmaxf(l1, l2));
        float lse = mxl + logf(expf(l0 - mxl) + expf(l1 - mxl) + expf(l2 - mxl));
        out[g * 3 + 0] = l0 - lse;
        out[g * 3 + 1] = l1 - lse;
        out[g * 3 + 2] = l2 - lse;
    }
}

// ---------------- launch ----------------

extern "C" void kernel_launch(void* const* d_in, const int* in_sizes, int n_in,
                              void* d_out, int out_size, void* d_ws, size_t ws_size,
                              hipStream_t stream) {
    const float* x   = (const float*)d_in[0];
    const int* ei    = (const int*)d_in[1];
    const int* src   = ei;
    const int* dst   = ei + N_EDGES;
    const int* batch = (const int*)d_in[2];
    const float *W1 = (const float*)d_in[3],  *b1 = (const float*)d_in[4];
    const float *g1 = (const float*)d_in[5],  *be1 = (const float*)d_in[6];
    const float *W2 = (const float*)d_in[7],  *b2 = (const float*)d_in[8];
    const float *g2 = (const float*)d_in[9],  *be2 = (const float*)d_in[10];
    const float *W3 = (const float*)d_in[11], *b3 = (const float*)d_in[12];
    const float *g3 = (const float*)d_in[13], *be3 = (const float*)d_in[14];
    const float *Wl = (const float*)d_in[15], *bl = (const float*)d_in[16];
    float* out = (float*)d_out;

    // workspace carve (4-byte words)
    int* base = (int*)d_ws;
    size_t o = 0;
    float* stats1 = (float*)(base + o); o += 256;
    float* stats2 = (float*)(base + o); o += 256;
    float* stats3 = (float*)(base + o); o += 256;
    int* gmax     = base + o; o += (size_t)N_GRAPHS * 128;
    size_t zero_words = o;                         // zeroed region
    int* gmin     = base + o; o += (size_t)N_GRAPHS * 128;   // memset 0x7F
    int* bbase    = base + o; o += NBIN + 4;
    int* ghist    = base + o; o += NBIN + 4;
    int* hists    = base + o; o += ((size_t)NBIN * NCHUNK + 3) & ~3ULL;
    float* W2p    = (float*)(base + o); o += 256;
    float* cw2    = (float*)(base + o); o += 32;
    __half* wfrag = (__half*)(base + o); o += 2048;
    float* cw3    = (float*)(base + o); o += 128;
    int* offs     = base + o; o += 100000;
    int* ends     = base + o; o += 100000;
    int* store    = base + o; o += STORE_CAP;
    int* csr      = base + o; o += STORE_CAP;
    float* dis    = (float*)(base + o); o += N_NODES;
    float* rdis   = (float*)(base + o); o += N_NODES;
    float* svec   = (float*)(base + o); o += N_NODES;
    float* spart  = (float*)(base + o); o += (size_t)NSTATB * 256;
    float4* xd    = (float4*)(base + o); o += (size_t)(N_NODES + 1) * 4;
    __half* ys1   = (__half*)(base + o); o += (size_t)(N_NODES + 1) * 4;
    __half* ys2   = (__half*)(base + o); o += (size_t)(N_NODES + 1) * 16;
    __half* u2    = (__half*)(base + o); o += (size_t)N_NODES * 16;
    __half* ys3   = (__half*)(base + o); o += (size_t)N_NODES * 64;
    if (ws_size < o * 4) return;

    const int TB = 256;

    hipMemsetAsync(base, 0, zero_words * 4, stream);
    hipMemsetAsync(gmin, 0x7F, (size_t)N_GRAPHS * 128 * 4, stream);

    // CSR build (padded radix, 512-node bins, direct scatter)
    k_hist2<<<NCHUNK, TB, 0, stream>>>(dst, hists);
    k_scan2<<<NBIN, 64, 0, stream>>>(hists, ghist);
    k_binscan<<<1, 512, 0, stream>>>(ghist, bbase);
    k_scatter<<<NCHUNK, TB, 0, stream>>>(src, dst, bbase, hists, store);
    k_csr_build<<<NBIN, 256, 0, stream>>>(bbase, store, x, offs, ends, dis, rdis, xd, csr);

    // layer 1 (4 nodes/wave, 16 nodes/block)
    k_agg1<<<N_NODES / 16, TB, 0, stream>>>(xd, offs, ends, csr, W1, b1, svec, ys1);
    k_stats<8><<<256, 256, 0, stream>>>(ys1, rdis, stats1);
    k_prep2<<<1, 256, 0, stream>>>(stats1, g1, be1, W2, W2p, cw2, ys1);

    // layer 2 (8 nodes/wave, 32 nodes/block)
    k_agg2<<<N_NODES / 32, TB, 0, stream>>>(ys1, offs, ends, csr, dis, svec, W2p, cw2, b2, ys2);
    k_stats<32><<<256, 256, 0, stream>>>(ys2, rdis, stats2);
    k_prep3<<<1, 512, 0, stream>>>(stats2, g2, be2, W3, wfrag, cw3, ys2);

    // layer 3
    k_agg3<<<(N_NODES + 3) / 4, TB, 0, stream>>>(ys2, offs, ends, csr, dis, u2);
    k_mm_mfma<<<(N_NODES + 63) / 64, 256, 0, stream>>>(u2, wfrag, cw3, b3, svec, dis, ys3);
    k_stats128<<<NSTATB, 256, 0, stream>>>(ys3, rdis, spart);
    k_stats_red<<<256, 256, 0, stream>>>(spart, stats3);

    // pool + head
    k_pool1<<<NSEGB, 128, 0, stream>>>(ys3, rdis, batch, gmax, gmin);
    k_poolhead<<<N_GRAPHS, 128, 0, stream>>>(gmax, gmin, batch, stats3, g3, be3, Wl, bl, out);
}

// Round 15
// 378.555 us; speedup vs baseline: 1.0906x; 1.0549x over previous
//
#include <hip/hip_runtime.h>
#include <hip/hip_bf16.h>
#include <hip/hip_fp16.h>
#include <math.h>

#define N_NODES 100000
#define N_EDGES 3200000
#define N_GRAPHS 512
#define BN_EPS 1e-5f
#define NBIN ((N_NODES + 511) / 512)            // 196 bins of 512 nodes
#define CHUNK 8192                              // edges per chunk
#define NCHUNK ((N_EDGES + CHUNK - 1) / CHUNK)  // 391
#define STORE_CAP (N_EDGES + 16 * NBIN * NCHUNK)  // padded store capacity
#define LSEG 98
#define NSEGB ((N_NODES + LSEG - 1) / LSEG)     // 1021 pool segments
#define NSTATB ((N_NODES + 127) / 128)          // 782 stats slabs

typedef _Float16 half8_t __attribute__((ext_vector_type(8)));
typedef float float4_t __attribute__((ext_vector_type(4)));

struct alignas(8) h4 { __half2 a, b; };
struct alignas(16) h8s { __half2 h[4]; };

// ---------------- CSR build: padded single-scatter radix, 512-node bins ----------------

__global__ void k_hist2(const int* __restrict__ dst, int* __restrict__ hists) {
    __shared__ int h[NBIN];
    for (int i = threadIdx.x; i < NBIN; i += blockDim.x) h[i] = 0;
    __syncthreads();
    int e0 = blockIdx.x * CHUNK;
    int e1 = min(e0 + CHUNK, N_EDGES);
    for (int e = e0 + threadIdx.x; e < e1; e += blockDim.x)
        atomicAdd(&h[dst[e] >> 9], 1);
    __syncthreads();
    for (int i = threadIdx.x; i < NBIN; i += blockDim.x)
        hists[i * NCHUNK + blockIdx.x] = h[i];
}

// per-bin exclusive scan over chunks of PADDED counts (pad to x16 -> 64B runs)
__global__ void k_scan2(int* __restrict__ hists, int* __restrict__ ghist) {
    int b = blockIdx.x;
    int lane = threadIdx.x;   // 64 threads
    int carry = 0;
    int base = b * NCHUNK;
    for (int c0 = 0; c0 < NCHUNK; c0 += 64) {
        int c = c0 + lane;
        int v = (c < NCHUNK) ? hists[base + c] : 0;
        int pv = (v + 15) & ~15;
        int inc = pv;
#pragma unroll
        for (int off = 1; off < 64; off <<= 1) {
            int u = __shfl_up(inc, off, 64);
            if (lane >= off) inc += u;
        }
        if (c < NCHUNK) hists[base + c] = inc - pv + carry;
        carry += __shfl(inc, 63, 64);
    }
    if (lane == 0) ghist[b] = carry;   // padded bin total
}

__global__ void k_binscan(const int* __restrict__ ghist, int* __restrict__ bbase) {
    __shared__ int sd[512];
    int t = threadIdx.x;
    int v = (t < NBIN) ? ghist[t] : 0;
    sd[t] = v;
    __syncthreads();
    for (int off = 1; off < 512; off <<= 1) {
        int u = (t >= off) ? sd[t - off] : 0;
        __syncthreads();
        sd[t] += u;
        __syncthreads();
    }
    if (t < NBIN) bbase[t] = sd[t] - v;
    if (t == 511) bbase[NBIN] = sd[511];   // padded grand total
}

// per-chunk direct scatter (391 blocks) + sentinel pad to 64B run boundaries
__global__ void k_scatter(const int* __restrict__ src, const int* __restrict__ dst,
                          const int* __restrict__ bbase, const int* __restrict__ hists,
                          int* __restrict__ store) {
    __shared__ int cur[NBIN];
    for (int i = threadIdx.x; i < NBIN; i += blockDim.x)
        cur[i] = bbase[i] + hists[i * NCHUNK + blockIdx.x];
    __syncthreads();
    int e0 = blockIdx.x * CHUNK;
    int e1 = min(e0 + CHUNK, N_EDGES);
    for (int e = e0 + threadIdx.x; e < e1; e += blockDim.x) {
        int d = dst[e];
        int b = d >> 9;
        int pos = atomicAdd(&cur[b], 1);
        store[pos] = (src[e] << 9) | (d & 511);
    }
    __syncthreads();
    // pad each run's tail to the 16-slot boundary -> every line fully written
    for (int i = threadIdx.x; i < NBIN; i += blockDim.x) {
        int p = cur[i];
        int end = (p + 15) & ~15;
        for (; p < end; ++p) store[p] = -1;
    }
}

// 1024 threads/block: count/scatter stride 1024, scan on threads 0-255
__global__ void k_csr_build(const int* __restrict__ bbase, const int* __restrict__ store,
                            const float* __restrict__ x, int* __restrict__ offs,
                            int* __restrict__ ends, float* __restrict__ dis,
                            float* __restrict__ rdis, float4* __restrict__ xd,
                            int* __restrict__ csr) {
    __shared__ int cnt[512], cur[512], wsum[4];
    int b = blockIdx.x;
    int n0 = b << 9;
    int e0 = bbase[b], e1 = bbase[b + 1];
    int t = threadIdx.x;
    int lane = t & 63, wid = t >> 6;
    if (t < 512) cnt[t] = 0;
    __syncthreads();
    for (int e = e0 + t; e < e1; e += 1024) {
        int p = store[e];
        if (p >= 0) atomicAdd(&cnt[p & 511], 1);
    }
    __syncthreads();
    // scan 512 counts on first 4 waves: thread t owns entries 2t, 2t+1
    int c0 = 0, c1 = 0, pair = 0, inc = 0;
    if (t < 256) {
        c0 = cnt[2 * t];
        c1 = cnt[2 * t + 1];
        pair = c0 + c1;
        inc = pair;
#pragma unroll
        for (int off = 1; off < 64; off <<= 1) {
            int u = __shfl_up(inc, off, 64);
            if (lane >= off) inc += u;
        }
        if (lane == 63) wsum[wid] = inc;
    }
    __syncthreads();
    if (t < 256) {
        int wo = 0;
        for (int w = 0; w < wid; ++w) wo += wsum[w];
        int ex = inc - pair + wo;
        cur[2 * t] = ex;
        cur[2 * t + 1] = ex + c0;
#pragma unroll
        for (int j = 0; j < 2; ++j) {
            int n = n0 + 2 * t + j;
            int cc = j ? c1 : c0;
            int exx = j ? ex + c0 : ex;
            if (n < N_NODES) {
                offs[n] = e0 + exx;
                ends[n] = e0 + exx + cc;
                float dn = rsqrtf(1.0f + (float)cc);
                dis[n] = dn;
                rdis[n] = sqrtf(1.0f + (float)cc);
                float2 xv = *(const float2*)(x + 2 * (size_t)n);
                xd[n] = make_float4(dn * xv.x, dn * xv.y, dn, 0.f);
            } else if (n == N_NODES) {
                xd[N_NODES] = make_float4(0.f, 0.f, 0.f, 0.f);
            }
        }
    }
    __syncthreads();
    for (int e = e0 + t; e < e1; e += 1024) {
        int p = store[e];
        if (p >= 0) {
            int pos = e0 + atomicAdd(&cur[p & 511], 1);
            csr[pos] = p >> 9;
        }
    }
}

// ---------------- layer 1: 4 nodes/wave, aggregate xd + fused 2->8 mm + relu ----------------

__global__ void k_agg1(const float4* __restrict__ xd, const int* __restrict__ offs,
                       const int* __restrict__ ends, const int* __restrict__ csr,
                       const float* __restrict__ W1, const float* __restrict__ b1,
                       float* __restrict__ svec, __half* __restrict__ ys1) {
    __shared__ float sW[16], sb[8];
    int t = threadIdx.x;
    if (t < 16) sW[t] = W1[t];
    if (t < 8) sb[t] = b1[t];
    __syncthreads();
    int wave = t >> 6, lane = t & 63;
    int nsub = lane >> 4, eg = lane & 15;
    int node = ((blockIdx.x * 4 + wave) << 2) + nsub;   // exact: 100000 = 25000*4
    int e0 = offs[node], e1 = ends[node];
    float ax = 0.f, ay = 0.f, as = 0.f;
    for (int e = e0 + eg; e < e1; e += 32) {
        int s0 = csr[e];
        int s1 = (e + 16 < e1) ? csr[e + 16] : N_NODES;
        float4 v0 = xd[s0];
        float4 v1 = xd[s1];
        ax += v0.x + v1.x;
        ay += v0.y + v1.y;
        as += v0.z + v1.z;
    }
#pragma unroll
    for (int off = 1; off < 16; off <<= 1) {
        ax += __shfl_xor(ax, off, 64);
        ay += __shfl_xor(ay, off, 64);
        as += __shfl_xor(as, off, 64);
    }
    if (eg == 0) {
        float4 xn = xd[node];
        float dn = xn.z;
        float u0x = dn * (ax + xn.x);
        float u0y = dn * (ay + xn.y);
        svec[node] = dn * (as + xn.z);
        float y[8];
#pragma unroll
        for (int f = 0; f < 8; ++f)
            y[f] = dn * fmaxf(u0x * sW[f] + u0y * sW[8 + f] + sb[f], 0.f);
        h8s o;
#pragma unroll
        for (int q = 0; q < 4; ++q) o.h[q] = __floats2half2_rn(y[2 * q], y[2 * q + 1]);
        *(h8s*)(ys1 + (size_t)node * 8) = o;
    }
}

// ---------------- prep2: bn fold into W2; zero row ys1[N] ----------------

__global__ void k_prep2(const float* __restrict__ stats, const float* __restrict__ gamma,
                        const float* __restrict__ beta, const float* __restrict__ W2,
                        float* __restrict__ W2p, float* __restrict__ cw2,
                        __half* __restrict__ ys1) {
    __shared__ float a1[8], c1[8];
    int t = threadIdx.x;   // 256
    if (t < 8) {
        float inv_n = 1.0f / (float)N_NODES;
        float m = stats[t] * inv_n;
        float v = stats[8 + t] * inv_n - m * m;
        float a = gamma[t] * rsqrtf(v + BN_EPS);
        a1[t] = a;
        c1[t] = beta[t] - m * a;
    }
    __syncthreads();
    W2p[t] = a1[t >> 5] * W2[t];    // 8x32 = 256
    if (t < 32) {
        float cb = 0.f;
#pragma unroll
        for (int i = 0; i < 8; ++i) cb += c1[i] * W2[i * 32 + t];
        cw2[t] = cb;
    }
    if (t == 128) *(int4*)(ys1 + (size_t)N_NODES * 8) = make_int4(0, 0, 0, 0);
}

// ---------------- layer 2: 8 nodes/wave, aggregate ys1 (width 8) + fused 8->32 mm ----------------

__global__ void k_agg2(const __half* __restrict__ ys1, const int* __restrict__ offs,
                       const int* __restrict__ ends, const int* __restrict__ csr,
                       const float* __restrict__ dis, const float* __restrict__ svec,
                       const float* __restrict__ W2p, const float* __restrict__ cw2,
                       const float* __restrict__ b2, __half* __restrict__ ys2) {
    __shared__ float sW[256], sC[32], sB[32];
    int t = threadIdx.x;
    sW[t] = W2p[t];
    if (t < 32) { sC[t] = cw2[t]; sB[t] = b2[t]; }
    __syncthreads();
    int wave = t >> 6, lane = t & 63;
    int nsub = lane >> 3, eg = (lane >> 1) & 3, chunk = lane & 1;
    int node = ((blockIdx.x * 4 + wave) << 3) + nsub;   // exact: 100000 = 12500*8
    int e0 = offs[node], e1 = ends[node];
    float a0 = 0.f, a1 = 0.f, a2 = 0.f, a3 = 0.f;
    const __half* hp = ys1 + chunk * 4;
    for (int e = e0 + eg; e < e1; e += 8) {
        int s0 = csr[e];
        int s1 = (e + 4 < e1) ? csr[e + 4] : N_NODES;
        h4 v0 = *(const h4*)(hp + (size_t)s0 * 8);
        h4 v1 = *(const h4*)(hp + (size_t)s1 * 8);
        a0 += __low2float(v0.a) + __low2float(v1.a);
        a1 += __high2float(v0.a) + __high2float(v1.a);
        a2 += __low2float(v0.b) + __low2float(v1.b);
        a3 += __high2float(v0.b) + __high2float(v1.b);
    }
    if (eg == 0) {   // self-loop
        h4 v = *(const h4*)(hp + (size_t)node * 8);
        a0 += __low2float(v.a);
        a1 += __high2float(v.a);
        a2 += __low2float(v.b);
        a3 += __high2float(v.b);
    }
#pragma unroll
    for (int off = 2; off < 8; off <<= 1) {
        a0 += __shfl_xor(a0, off, 64);
        a1 += __shfl_xor(a1, off, 64);
        a2 += __shfl_xor(a2, off, 64);
        a3 += __shfl_xor(a3, off, 64);
    }
    int lb = nsub << 3;
    float u[8];
    u[0] = __shfl(a0, lb, 64);     u[1] = __shfl(a1, lb, 64);
    u[2] = __shfl(a2, lb, 64);     u[3] = __shfl(a3, lb, 64);
    u[4] = __shfl(a0, lb + 1, 64); u[5] = __shfl(a1, lb + 1, 64);
    u[6] = __shfl(a2, lb + 1, 64); u[7] = __shfl(a3, lb + 1, 64);
    float dn = dis[node];
    float sv = svec[node];
#pragma unroll
    for (int i = 0; i < 8; ++i) u[i] *= dn;
    int c0 = (lane & 7) * 4;
    float y[4];
#pragma unroll
    for (int k = 0; k < 4; ++k) {
        int col = c0 + k;
        float conv = sB[col] + sv * sC[col];
#pragma unroll
        for (int i = 0; i < 8; ++i) conv += u[i] * sW[i * 32 + col];
        y[k] = dn * fmaxf(conv, 0.f);
    }
    h4 o;
    o.a = __floats2half2_rn(y[0], y[1]);
    o.b = __floats2half2_rn(y[2], y[3]);
    *(h4*)(ys2 + (size_t)node * 32 + c0) = o;
}

// ---------------- prep3 ----------------

__global__ void k_prep3(const float* __restrict__ stats, const float* __restrict__ gamma,
                        const float* __restrict__ beta, const float* __restrict__ W3,
                        __half* __restrict__ wfrag, float* __restrict__ cw3,
                        __half* __restrict__ ys2) {
    __shared__ float a2[32], c2[32];
    int t = threadIdx.x;   // 512
    if (t < 32) {
        float inv_n = 1.0f / (float)N_NODES;
        float m = stats[t] * inv_n;
        float v = stats[32 + t] * inv_n - m * m;
        float a = gamma[t] * rsqrtf(v + BN_EPS);
        a2[t] = a;
        c2[t] = beta[t] - m * a;
    }
    __syncthreads();
    {
        int g = t >> 6, kq = (t >> 4) & 3, c = t & 15;
#pragma unroll
        for (int j = 0; j < 8; ++j) {
            int k = kq * 8 + j;
            wfrag[(size_t)t * 8 + j] = __float2half(a2[k] * W3[k * 128 + g * 16 + c]);
        }
    }
    if (t < 128) {
        float cb = 0.f;
#pragma unroll
        for (int k = 0; k < 32; ++k) cb += c2[k] * W3[k * 128 + t];
        cw3[t] = cb;
    }
    if (t >= 480 && t < 496)
        ((__half2*)(ys2 + (size_t)N_NODES * 32))[t - 480] =
            __half2{__float2half(0.f), __float2half(0.f)};
}

// ---------------- layer 3 aggregation: ys2 (width 32) -> u2 ----------------

__global__ void k_agg3(const __half* __restrict__ ys2, const int* __restrict__ offs,
                       const int* __restrict__ ends, const int* __restrict__ csr,
                       const float* __restrict__ dis, __half* __restrict__ u2) {
    int wave = threadIdx.x >> 6;
    int lane = threadIdx.x & 63;
    int node = blockIdx.x * 4 + wave;
    if (node >= N_NODES) return;
    int chunk = lane & 7;
    int eg = lane >> 3;
    int e0 = offs[node], e1 = ends[node];
    float ax = 0.f, ay = 0.f, az = 0.f, aw = 0.f;
    const __half* hp = ys2 + (size_t)chunk * 4;
    for (int e = e0 + eg; e < e1; e += 32) {
        int s0 = csr[e];
        int s1 = (e + 8 < e1) ? csr[e + 8] : N_NODES;
        int s2 = (e + 16 < e1) ? csr[e + 16] : N_NODES;
        int s3 = (e + 24 < e1) ? csr[e + 24] : N_NODES;
        h4 v0 = *(const h4*)(hp + (size_t)s0 * 32);
        h4 v1 = *(const h4*)(hp + (size_t)s1 * 32);
        h4 v2 = *(const h4*)(hp + (size_t)s2 * 32);
        h4 v3 = *(const h4*)(hp + (size_t)s3 * 32);
        ax += __low2float(v0.a) + __low2float(v1.a) + __low2float(v2.a) + __low2float(v3.a);
        ay += __high2float(v0.a) + __high2float(v1.a) + __high2float(v2.a) + __high2float(v3.a);
        az += __low2float(v0.b) + __low2float(v1.b) + __low2float(v2.b) + __low2float(v3.b);
        aw += __high2float(v0.b) + __high2float(v1.b) + __high2float(v2.b) + __high2float(v3.b);
    }
    if (eg == 0) {
        h4 v = *(const h4*)(hp + (size_t)node * 32);
        ax += __low2float(v.a);
        ay += __high2float(v.a);
        az += __low2float(v.b);
        aw += __high2float(v.b);
    }
#pragma unroll
    for (int off = 8; off < 64; off <<= 1) {
        ax += __shfl_xor(ax, off, 64);
        ay += __shfl_xor(ay, off, 64);
        az += __shfl_xor(az, off, 64);
        aw += __shfl_xor(aw, off, 64);
    }
    if (lane < 8) {
        float dn = dis[node];
        h4 o;
        o.a = __floats2half2_rn(dn * ax, dn * ay);
        o.b = __floats2half2_rn(dn * az, dn * aw);
        *(h4*)(u2 + (size_t)node * 32 + chunk * 4) = o;
    }
}

// ---------------- layer 3 transform via MFMA ----------------

__global__ void k_mm_mfma(const __half* __restrict__ u2, const __half* __restrict__ wfrag,
                          const float* __restrict__ cw3, const float* __restrict__ b3,
                          const float* __restrict__ svec, const float* __restrict__ dis,
                          __half* __restrict__ ys3) {
    int wave = threadIdx.x >> 6;
    int lane = threadIdx.x & 63;
    int n0 = (blockIdx.x * 4 + wave) * 16;
    if (n0 >= N_NODES) return;
    int m = lane & 15;
    int kq = lane >> 4;

    half8_t af = *(const half8_t*)(u2 + (size_t)(n0 + m) * 32 + kq * 8);

    float4_t accs[8];
#pragma unroll
    for (int g = 0; g < 8; ++g) {
        float4_t acc = {0.f, 0.f, 0.f, 0.f};
        half8_t bf = *(const half8_t*)(wfrag + (size_t)((g * 4 + kq) * 16 + m) * 8);
        accs[g] = __builtin_amdgcn_mfma_f32_16x16x32_f16(af, bf, acc, 0, 0, 0);
    }
    float sv[4], dn[4];
#pragma unroll
    for (int r = 0; r < 4; ++r) {
        sv[r] = svec[n0 + kq * 4 + r];
        dn[r] = dis[n0 + kq * 4 + r];
    }
#pragma unroll
    for (int g = 0; g < 8; ++g) {
        float cwf = cw3[g * 16 + m];
        float bf3 = b3[g * 16 + m];
#pragma unroll
        for (int r = 0; r < 4; ++r) {
            float y = fmaxf(accs[g][r] + sv[r] * cwf + bf3, 0.f);
            ys3[(size_t)(n0 + kq * 4 + r) * 128 + g * 16 + m] = __float2half(dn[r] * y);
        }
    }
}

// ---------------- BN stats over y = ys * rdis (small widths: 8/32) ----------------

template <int FOUT>
__global__ void k_stats(const __half* __restrict__ ys, const float* __restrict__ rdis,
                        float* __restrict__ stats) {
    constexpr int GP = 256 / FOUT;
    int f = threadIdx.x % FOUT, g = threadIdx.x / FOUT;
    float s = 0.f, s2 = 0.f;
    for (int n = blockIdx.x * GP + g; n < N_NODES; n += gridDim.x * GP) {
        float v = __half2float(ys[(size_t)n * FOUT + f]) * rdis[n];
        s += v;
        s2 += v * v;
    }
    __shared__ float ls[256], ls2[256];
    ls[threadIdx.x] = s;
    ls2[threadIdx.x] = s2;
    __syncthreads();
    if (g == 0) {
        for (int gg = 1; gg < GP; ++gg) {
            s += ls[gg * FOUT + f];
            s2 += ls2[gg * FOUT + f];
        }
        atomicAdd(&stats[f], s);
        atomicAdd(&stats[FOUT + f], s2);
    }
}

// ---------------- BN stats width 128: two-phase vectorized ----------------

__global__ void k_stats128(const __half* __restrict__ ys, const float* __restrict__ rdis,
                           float* __restrict__ part) {
    int t = threadIdx.x;
    int chunk = t & 15, row = t >> 4;
    int n0 = blockIdx.x * 128;
    float s[8] = {0, 0, 0, 0, 0, 0, 0, 0};
    float s2[8] = {0, 0, 0, 0, 0, 0, 0, 0};
#pragma unroll
    for (int i = 0; i < 8; ++i) {
        int n = n0 + i * 16 + row;
        if (n < N_NODES) {
            float r = rdis[n];
            h8s v = *(const h8s*)(ys + (size_t)n * 128 + chunk * 8);
#pragma unroll
            for (int q = 0; q < 4; ++q) {
                float v0 = __low2float(v.h[q]) * r;
                float v1 = __high2float(v.h[q]) * r;
                s[2 * q] += v0;  s2[2 * q] += v0 * v0;
                s[2 * q + 1] += v1;  s2[2 * q + 1] += v1 * v1;
            }
        }
    }
#pragma unroll
    for (int off = 16; off < 64; off <<= 1)
#pragma unroll
        for (int j = 0; j < 8; ++j) {
            s[j] += __shfl_xor(s[j], off, 64);
            s2[j] += __shfl_xor(s2[j], off, 64);
        }
    __shared__ float sm[256];
    sm[t] = 0.f;
    __syncthreads();
    if ((t & 63) < 16) {
#pragma unroll
        for (int j = 0; j < 8; ++j) {
            atomicAdd(&sm[chunk * 8 + j], s[j]);
            atomicAdd(&sm[128 + chunk * 8 + j], s2[j]);
        }
    }
    __syncthreads();
    part[(size_t)blockIdx.x * 256 + t] = sm[t];
}

__global__ void k_stats_red(const float* __restrict__ part, float* __restrict__ stats) {
    int i = blockIdx.x;   // 0..255
    int t = threadIdx.x;  // 256
    float s = 0.f;
    for (int b = t; b < NSTATB; b += 256) s += part[(size_t)b * 256 + i];
    __shared__ float sm[256];
    sm[t] = s;
    __syncthreads();
    for (int st = 128; st > 0; st >>= 1) {
        if (t < st) sm[t] += sm[t + st];
        __syncthreads();
    }
    if (t == 0) stats[i] = sm[0];
}

// ---------------- pooling: segment-parallel max/min ----------------

__global__ void k_pool1(const __half* __restrict__ ys3, const float* __restrict__ rdis,
                        const int* __restrict__ batch, int* __restrict__ gmax,
                        int* __restrict__ gmin) {
    __shared__ int sb[LSEG];
    __shared__ float sr[LSEG];
    int n0 = blockIdx.x * LSEG;
    int n1 = min(n0 + LSEG, N_NODES);
    int L = n1 - n0;
    int f = threadIdx.x;    // 128 threads = feature
    for (int i = f; i < L; i += 128) { sb[i] = batch[n0 + i]; sr[i] = rdis[n0 + i]; }
    __syncthreads();
    if (L <= 0) return;
    int cg = sb[0];
    int mx = 0;
    int mn = 0x7F800000;
    for (int i = 0; i < L; ++i) {
        int g = sb[i];
        if (g != cg) {
            atomicMax(&gmax[cg * 128 + f], mx);
            atomicMin(&gmin[cg * 128 + f], mn);
            cg = g; mx = 0; mn = 0x7F800000;
        }
        float v = __half2float(ys3[(size_t)(n0 + i) * 128 + f]) * sr[i];
        int b = __float_as_int(v);
        mx = max(mx, b);
        mn = min(mn, b);
    }
    atomicMax(&gmax[cg * 128 + f], mx);
    atomicMin(&gmin[cg * 128 + f], mn);
}

// ---------------- fused bn-affine + head + log_softmax ----------------

__device__ __forceinline__ int lower_bound_dev(const int* __restrict__ a, int val) {
    int lo = 0, hi = N_NODES;
    while (lo < hi) {
        int mid = (lo + hi) >> 1;
        if (a[mid] < val) lo = mid + 1; else hi = mid;
    }
    return lo;
}

__global__ void k_poolhead(const int* __restrict__ gmax, const int* __restrict__ gmin,
                           const int* __restrict__ batch, const float* __restrict__ stats,
                           const float* __restrict__ gamma, const float* __restrict__ beta,
                           const float* __restrict__ Wl, const float* __restrict__ bl,
                           float* __restrict__ out) {
    int g = blockIdx.x;
    int f = threadIdx.x;    // 128
    float inv_n = 1.0f / (float)N_NODES;
    float m = stats[f] * inv_n;
    float var = stats[128 + f] * inv_n - m * m;
    float a = gamma[f] * rsqrtf(var + BN_EPS);
    float c = beta[f] - m * a;
    int s = lower_bound_dev(batch, g);
    int e = lower_bound_dev(batch, g + 1);
    float mx = __int_as_float(gmax[g * 128 + f]);
    float mn = __int_as_float(gmin[g * 128 + f]);
    float r;
    if (e > s) r = (a >= 0.f) ? (a * mx + c) : (a * mn + c);
    else r = -INFINITY;
    __shared__ float l[3][128];
    l[0][f] = r * Wl[f * 3 + 0];
    l[1][f] = r * Wl[f * 3 + 1];
    l[2][f] = r * Wl[f * 3 + 2];
    __syncthreads();
    for (int st = 64; st > 0; st >>= 1) {
        if (f < st) {
            l[0][f] += l[0][f + st];
            l[1][f] += l[1][f + st];
            l[2][f] += l[2][f + st];
        }
        __syncthreads();
    }
    if (f == 0) {
        float l0 = l[0][0] + bl[0], l1 = l[1][0] + bl[1], l2 = l[2][0] + bl[2];
        float mxl = fmaxf(l0, fmaxf(l1, l2));
        float lse = mxl + logf(expf(l0 - mxl) + expf(l1 - mxl) + expf(l2 - mxl));
        out[g * 3 + 0] = l0 - lse;
        out[g * 3 + 1] = l1 - lse;
        out[g * 3 + 2] = l2 - lse;
    }
}

// ---------------- launch ----------------

extern "C" void kernel_launch(void* const* d_in, const int* in_sizes, int n_in,
                              void* d_out, int out_size, void* d_ws, size_t ws_size,
                              hipStream_t stream) {
    const float* x   = (const float*)d_in[0];
    const int* ei    = (const int*)d_in[1];
    const int* src   = ei;
    const int* dst   = ei + N_EDGES;
    const int* batch = (const int*)d_in[2];
    const float *W1 = (const float*)d_in[3],  *b1 = (const float*)d_in[4];
    const float *g1 = (const float*)d_in[5],  *be1 = (const float*)d_in[6];
    const float *W2 = (const float*)d_in[7],  *b2 = (const float*)d_in[8];
    const float *g2 = (const float*)d_in[9],  *be2 = (const float*)d_in[10];
    const float *W3 = (const float*)d_in[11], *b3 = (const float*)d_in[12];
    const float *g3 = (const float*)d_in[13], *be3 = (const float*)d_in[14];
    const float *Wl = (const float*)d_in[15], *bl = (const float*)d_in[16];
    float* out = (float*)d_out;

    // workspace carve (4-byte words)
    int* base = (int*)d_ws;
    size_t o = 0;
    float* stats1 = (float*)(base + o); o += 256;
    float* stats2 = (float*)(base + o); o += 256;
    float* stats3 = (float*)(base + o); o += 256;
    int* gmax     = base + o; o += (size_t)N_GRAPHS * 128;
    size_t zero_words = o;                         // zeroed region
    int* gmin     = base + o; o += (size_t)N_GRAPHS * 128;   // memset 0x7F
    int* bbase    = base + o; o += NBIN + 4;
    int* ghist    = base + o; o += NBIN + 4;
    int* hists    = base + o; o += ((size_t)NBIN * NCHUNK + 3) & ~3ULL;
    float* W2p    = (float*)(base + o); o += 256;
    float* cw2    = (float*)(base + o); o += 32;
    __half* wfrag = (__half*)(base + o); o += 2048;
    float* cw3    = (float*)(base + o); o += 128;
    int* offs     = base + o; o += 100000;
    int* ends     = base + o; o += 100000;
    int* store    = base + o; o += STORE_CAP;
    int* csr      = base + o; o += STORE_CAP;
    float* dis    = (float*)(base + o); o += N_NODES;
    float* rdis   = (float*)(base + o); o += N_NODES;
    float* svec   = (float*)(base + o); o += N_NODES;
    float* spart  = (float*)(base + o); o += (size_t)NSTATB * 256;
    float4* xd    = (float4*)(base + o); o += (size_t)(N_NODES + 1) * 4;
    __half* ys1   = (__half*)(base + o); o += (size_t)(N_NODES + 1) * 4;
    __half* ys2   = (__half*)(base + o); o += (size_t)(N_NODES + 1) * 16;
    __half* u2    = (__half*)(base + o); o += (size_t)N_NODES * 16;
    __half* ys3   = (__half*)(base + o); o += (size_t)N_NODES * 64;
    if (ws_size < o * 4) return;

    const int TB = 256;

    hipMemsetAsync(base, 0, zero_words * 4, stream);
    hipMemsetAsync(gmin, 0x7F, (size_t)N_GRAPHS * 128 * 4, stream);

    // CSR build (padded radix, 512-node bins, direct scatter)
    k_hist2<<<NCHUNK, TB, 0, stream>>>(dst, hists);
    k_scan2<<<NBIN, 64, 0, stream>>>(hists, ghist);
    k_binscan<<<1, 512, 0, stream>>>(ghist, bbase);
    k_scatter<<<NCHUNK, TB, 0, stream>>>(src, dst, bbase, hists, store);
    k_csr_build<<<NBIN, 1024, 0, stream>>>(bbase, store, x, offs, ends, dis, rdis, xd, csr);

    // layer 1 (4 nodes/wave, 16 nodes/block)
    k_agg1<<<N_NODES / 16, TB, 0, stream>>>(xd, offs, ends, csr, W1, b1, svec, ys1);
    k_stats<8><<<256, 256, 0, stream>>>(ys1, rdis, stats1);
    k_prep2<<<1, 256, 0, stream>>>(stats1, g1, be1, W2, W2p, cw2, ys1);

    // layer 2 (8 nodes/wave, 32 nodes/block)
    k_agg2<<<N_NODES / 32, TB, 0, stream>>>(ys1, offs, ends, csr, dis, svec, W2p, cw2, b2, ys2);
    k_stats<32><<<256, 256, 0, stream>>>(ys2, rdis, stats2);
    k_prep3<<<1, 512, 0, stream>>>(stats2, g2, be2, W3, wfrag, cw3, ys2);

    // layer 3
    k_agg3<<<(N_NODES + 3) / 4, TB, 0, stream>>>(ys2, offs, ends, csr, dis, u2);
    k_mm_mfma<<<(N_NODES + 63) / 64, 256, 0, stream>>>(u2, wfrag, cw3, b3, svec, dis, ys3);
    k_stats128<<<NSTATB, 256, 0, stream>>>(ys3, rdis, spart);
    k_stats_red<<<256, 256, 0, stream>>>(spart, stats3);

    // pool + head
    k_pool1<<<NSEGB, 128, 0, stream>>>(ys3, rdis, batch, gmax, gmin);
    k_poolhead<<<N_GRAPHS, 128, 0, stream>>>(gmax, gmin, batch, stats3, g3, be3, Wl, bl, out);
}